// Round 1
// baseline (59.012 us; speedup 1.0000x reference)
//
#include <hip/hip_runtime.h>
#include <hip/hip_bf16.h>

// Problem-fixed shapes (XLMRForTokenClassification: B=128, S=512, H=1024, L=9)
#define B_ 128
#define S_ 512
#define H_ 1024
#define L_ 9
#define K2_BLOCKS 1024
#define K2_THREADS 256
#define WAVES_PER_BLK (K2_THREADS / 64)

// ---------------------------------------------------------------------------
// Kernel 1: per batch, build inverse stable-partition map.
// src_of[b][j] = original position s of the j-th valid token (bpe==1), in
// original order; -1 for j >= n_valid (those rows are zeroed by the ref).
// One block per batch, 512 threads (= S), ballot + popcount prefix scan.
// ---------------------------------------------------------------------------
__global__ void build_src_of_kernel(const int* __restrict__ bpe,
                                    int* __restrict__ src_of) {
    const int b    = blockIdx.x;
    const int s    = threadIdx.x;        // 0..511
    const int lane = s & 63;
    const int wave = s >> 6;             // 0..7

    __shared__ int wcnt[S_ / 64];

    const int v = (bpe[b * S_ + s] == 1) ? 1 : 0;
    const unsigned long long ball = __ballot(v != 0);
    const int rank_in_wave = (int)__popcll(ball & ((1ull << lane) - 1ull));
    if (lane == 0) wcnt[wave] = (int)__popcll(ball);
    __syncthreads();

    int prefix = 0, n_valid = 0;
#pragma unroll
    for (int w = 0; w < S_ / 64; ++w) {
        const int c = wcnt[w];
        if (w < wave) prefix += c;
        n_valid += c;
    }

    if (v) src_of[b * S_ + prefix + rank_in_wave] = s;
    if (s >= n_valid) src_of[b * S_ + s] = -1;
}

// ---------------------------------------------------------------------------
// Kernel 2: one wave per (b, j) position, grid-stride.
// W (9 x 1024 f32) lives in registers: 36 float4 per lane, loaded once per
// wave and reused across ~16 positions. Active positions with src>=0 read one
// 4 KB coalesced row of x; dot-9 via per-lane FMA + 6-step shfl_xor butterfly.
// Inactive positions skipped; src<0 (zero row) -> logits = bias exactly.
// Block partials written to workspace (deterministic; no global atomics).
// ---------------------------------------------------------------------------
__global__ __launch_bounds__(K2_THREADS) void head_loss_kernel(
    const float* __restrict__ x,       // [B,S,H]
    const int*   __restrict__ labels,  // [B,S]
    const int*   __restrict__ lmask,   // [B,S]
    const int*   __restrict__ src_of,  // [B,S]
    const float* __restrict__ W,       // [L,H]
    const float* __restrict__ bias,    // [L]
    float* __restrict__ part_sum,      // [gridDim.x]
    float* __restrict__ part_cnt)      // [gridDim.x]
{
    const int lane      = threadIdx.x & 63;
    const int wv_in_blk = threadIdx.x >> 6;
    const int wid       = blockIdx.x * WAVES_PER_BLK + wv_in_blk;
    const int nwaves    = gridDim.x * WAVES_PER_BLK;

    // Stage W into registers: wreg[l][k] covers element (lane + 64*k)*4 .. +3
    const float4* W4 = reinterpret_cast<const float4*>(W);
    float4 wreg[L_][4];
#pragma unroll
    for (int l = 0; l < L_; ++l)
#pragma unroll
        for (int k = 0; k < 4; ++k)
            wreg[l][k] = W4[l * (H_ / 4) + lane + 64 * k];

    float bl[L_];
#pragma unroll
    for (int l = 0; l < L_; ++l) bl[l] = bias[l];

    float lsum = 0.f, lcnt = 0.f;

    for (int pos = wid; pos < B_ * S_; pos += nwaves) {
        const int lab = labels[pos];
        const bool active = (lmask[pos] == 1) && (lab != 0);
        if (!active) continue;   // wave-uniform branch

        const int src = src_of[pos];
        float logit[L_];
        if (src >= 0) {
            const int brow = pos >> 9;  // pos / S_
            const float4* x4 = reinterpret_cast<const float4*>(x)
                             + (size_t)(brow * S_ + src) * (H_ / 4);
            float acc[L_];
#pragma unroll
            for (int l = 0; l < L_; ++l) acc[l] = 0.f;
#pragma unroll
            for (int k = 0; k < 4; ++k) {
                const float4 xv = x4[lane + 64 * k];
#pragma unroll
                for (int l = 0; l < L_; ++l) {
                    acc[l] += xv.x * wreg[l][k].x + xv.y * wreg[l][k].y
                            + xv.z * wreg[l][k].z + xv.w * wreg[l][k].w;
                }
            }
            // butterfly reduce 9 values across 64 lanes
#pragma unroll
            for (int off = 32; off > 0; off >>= 1) {
#pragma unroll
                for (int l = 0; l < L_; ++l)
                    acc[l] += __shfl_xor(acc[l], off, 64);
            }
#pragma unroll
            for (int l = 0; l < L_; ++l) logit[l] = acc[l] + bl[l];
        } else {
            // zeroed row: logits are exactly the bias
#pragma unroll
            for (int l = 0; l < L_; ++l) logit[l] = bl[l];
        }

        // stable log-softmax NLL (all lanes redundantly; identical values)
        float m = logit[0];
#pragma unroll
        for (int l = 1; l < L_; ++l) m = fmaxf(m, logit[l]);
        float se = 0.f;
#pragma unroll
        for (int l = 0; l < L_; ++l) se += __expf(logit[l] - m);
        const float lse = m + __logf(se);
        const float nll = lse - logit[lab];

        lsum += nll;
        lcnt += 1.f;
    }

    __shared__ float ssum[WAVES_PER_BLK], scnt[WAVES_PER_BLK];
    if (lane == 0) { ssum[wv_in_blk] = lsum; scnt[wv_in_blk] = lcnt; }
    __syncthreads();
    if (threadIdx.x == 0) {
        float a = 0.f, c = 0.f;
#pragma unroll
        for (int w = 0; w < WAVES_PER_BLK; ++w) { a += ssum[w]; c += scnt[w]; }
        part_sum[blockIdx.x] = a;
        part_cnt[blockIdx.x] = c;
    }
}

// ---------------------------------------------------------------------------
// Kernel 3: reduce partials -> scalar loss
// ---------------------------------------------------------------------------
__global__ void finalize_kernel(const float* __restrict__ part_sum,
                                const float* __restrict__ part_cnt,
                                float* __restrict__ out) {
    const int lane = threadIdx.x;  // 64 threads
    float s = 0.f, c = 0.f;
    for (int i = lane; i < K2_BLOCKS; i += 64) {
        s += part_sum[i];
        c += part_cnt[i];
    }
#pragma unroll
    for (int off = 32; off > 0; off >>= 1) {
        s += __shfl_xor(s, off, 64);
        c += __shfl_xor(c, off, 64);
    }
    if (lane == 0) out[0] = s / fmaxf(c, 1.0f);
}

extern "C" void kernel_launch(void* const* d_in, const int* in_sizes, int n_in,
                              void* d_out, int out_size, void* d_ws, size_t ws_size,
                              hipStream_t stream) {
    const float* x      = (const float*)d_in[0];  // [B,S,H] f32
    const int*   labels = (const int*)d_in[1];    // [B,S]
    const int*   lmask  = (const int*)d_in[2];    // [B,S]
    const int*   bpe    = (const int*)d_in[3];    // [B,S]
    const float* W      = (const float*)d_in[4];  // [L,H] f32
    const float* bias   = (const float*)d_in[5];  // [L]  f32

    // Workspace layout: src_of [B*S] int32, then partial sums/counts.
    int*   src_of   = (int*)d_ws;
    float* part_sum = (float*)((char*)d_ws + (size_t)B_ * S_ * sizeof(int));
    float* part_cnt = part_sum + K2_BLOCKS;

    build_src_of_kernel<<<B_, S_, 0, stream>>>(bpe, src_of);
    head_loss_kernel<<<K2_BLOCKS, K2_THREADS, 0, stream>>>(
        x, labels, lmask, src_of, W, bias, part_sum, part_cnt);
    finalize_kernel<<<1, 64, 0, stream>>>(part_sum, part_cnt, (float*)d_out);
}

// Round 2
// 41.841 us; speedup vs baseline: 1.4104x; 1.4104x over previous
//
#include <hip/hip_runtime.h>
#include <hip/hip_bf16.h>

// Problem-fixed shapes (XLMRForTokenClassification: B=128, S=512, H=1024, L=9)
#define B_ 128
#define S_ 512
#define H_ 1024
#define L_ 9

#define MAIN_BLOCKS  512
#define MAIN_THREADS 256
#define WPB          (MAIN_THREADS / 64)       // waves per block = 4
#define SLOTS_PER_WAVE 32                      // 512*4 waves * 32 slots = 65536

// DPP-based wave64 sum: result lands in lane 63 (classic GCN sequence:
// row_shr:1/2/4/8 then row_bcast:15 (rows 1,3) and row_bcast:31 (rows 2,3)).
// Formulated as v += dpp_move(v); masked-off lanes get old=0 -> add 0.
#define DPP_ADD_(v, ctrl, rm, bm)                                              \
    v += __int_as_float(__builtin_amdgcn_update_dpp(                           \
        0, __float_as_int(v), ctrl, rm, bm, true))

__device__ __forceinline__ float wave_sum63(float v) {
    DPP_ADD_(v, 0x111, 0xf, 0xf);  // row_shr:1
    DPP_ADD_(v, 0x112, 0xf, 0xf);  // row_shr:2
    DPP_ADD_(v, 0x114, 0xf, 0xe);  // row_shr:4
    DPP_ADD_(v, 0x118, 0xf, 0xc);  // row_shr:8
    DPP_ADD_(v, 0x142, 0xa, 0xf);  // row_bcast:15 -> rows 1,3
    DPP_ADD_(v, 0x143, 0xc, 0xf);  // row_bcast:31 -> rows 2,3
    return v;                      // lane 63 holds the 64-lane total
}

// ---------------------------------------------------------------------------
// Kernel 1: per batch (one block of 512 threads):
//  - stable-partition scan -> srcbuf (the s-th valid original position)
//  - packed worklist entry per slot: (src<<8)|lab for active row-positions,
//    0xFFFFFFFF otherwise
//  - bias-only active positions (s >= n_valid: gathered row is zeros, so
//    logits == bias exactly): nll folded analytically into biassum[b]
//  - actcnt[b] = total active positions (the loss denominator)
// ---------------------------------------------------------------------------
__global__ void prep_kernel(const int* __restrict__ bpe,
                            const int* __restrict__ labels,
                            const int* __restrict__ lmask,
                            const float* __restrict__ bias,
                            unsigned* __restrict__ work,
                            float* __restrict__ biassum,
                            float* __restrict__ actcnt) {
    const int b    = blockIdx.x;
    const int s    = threadIdx.x;   // 0..511
    const int lane = s & 63;
    const int wave = s >> 6;        // 0..7

    __shared__ int   wcnt[S_ / 64];
    __shared__ int   srcbuf[S_];
    __shared__ float rsum[S_ / 64], rcnt[S_ / 64];

    const int v = (bpe[b * S_ + s] == 1) ? 1 : 0;
    const unsigned long long ball = __ballot(v != 0);
    const int rank = (int)__popcll(ball & ((1ull << lane) - 1ull));
    if (lane == 0) wcnt[wave] = (int)__popcll(ball);
    __syncthreads();

    int prefix = 0, n_valid = 0;
#pragma unroll
    for (int w = 0; w < S_ / 64; ++w) {
        const int c = wcnt[w];
        if (w < wave) prefix += c;
        n_valid += c;
    }
    if (v) srcbuf[prefix + rank] = s;
    __syncthreads();

    const int lab = labels[b * S_ + s];
    const bool act = (lmask[b * S_ + s] == 1) && (lab != 0);

    unsigned ent = 0xFFFFFFFFu;
    float bnll = 0.f;
    if (act && s < n_valid)
        ent = ((unsigned)srcbuf[s] << 8) | (unsigned)lab;
    work[b * S_ + s] = ent;

    if (act && s >= n_valid) {
        // zeroed row -> logits == bias exactly
        float mx = bias[0];
#pragma unroll
        for (int l = 1; l < L_; ++l) mx = fmaxf(mx, bias[l]);
        float se = 0.f;
#pragma unroll
        for (int l = 0; l < L_; ++l) se += __expf(bias[l] - mx);
        bnll = mx + __logf(se) - bias[lab];
    }

    float c = act ? 1.f : 0.f;
#pragma unroll
    for (int off = 32; off > 0; off >>= 1) {
        bnll += __shfl_xor(bnll, off, 64);
        c    += __shfl_xor(c, off, 64);
    }
    if (lane == 0) { rsum[wave] = bnll; rcnt[wave] = c; }
    __syncthreads();
    if (s == 0) {
        float a = 0.f, cc = 0.f;
#pragma unroll
        for (int w = 0; w < S_ / 64; ++w) { a += rsum[w]; cc += rcnt[w]; }
        biassum[b] = a;
        actcnt[b]  = cc;
    }
}

// ---------------------------------------------------------------------------
// Kernel 2: one wave owns 32 worklist slots. Loads all 32 entries with a
// single coalesced instruction, ballots the valid ones, walks set bits with
// readlane (scalar -> no per-item broadcast-load latency), processes items in
// software-pipelined pairs (2 rows of x in flight), reduces the 9 dots with
// DPP (VALU pipe, no LDS). W (9x1024 f32) stays in registers per wave.
// ---------------------------------------------------------------------------
__global__ __launch_bounds__(MAIN_THREADS) void head_loss_kernel(
    const float* __restrict__ x,     // [B,S,H]
    const float* __restrict__ W,     // [L,H]
    const float* __restrict__ bias,  // [L]
    const unsigned* __restrict__ work,
    float* __restrict__ part)        // [MAIN_BLOCKS]
{
    const int lane = threadIdx.x & 63;
    const int wv   = threadIdx.x >> 6;
    const int wid  = blockIdx.x * WPB + wv;

    const float4* W4 = reinterpret_cast<const float4*>(W);
    float4 wreg[L_][4];
#pragma unroll
    for (int l = 0; l < L_; ++l)
#pragma unroll
        for (int k = 0; k < 4; ++k)
            wreg[l][k] = W4[l * (H_ / 4) + lane + 64 * k];

    float bl[L_];
#pragma unroll
    for (int l = 0; l < L_; ++l) bl[l] = bias[l];

    unsigned e = 0xFFFFFFFFu;
    if (lane < SLOTS_PER_WAVE) e = work[wid * SLOTS_PER_WAVE + lane];
    unsigned long long m = __ballot(e != 0xFFFFFFFFu);

    const float4* X4 = reinterpret_cast<const float4*>(x);
    float lsum = 0.f;

    auto compute = [&](unsigned ev, float4 v0, float4 v1, float4 v2, float4 v3) {
        float acc[L_];
#pragma unroll
        for (int l = 0; l < L_; ++l) {
            acc[l] = v0.x * wreg[l][0].x + v0.y * wreg[l][0].y
                   + v0.z * wreg[l][0].z + v0.w * wreg[l][0].w
                   + v1.x * wreg[l][1].x + v1.y * wreg[l][1].y
                   + v1.z * wreg[l][1].z + v1.w * wreg[l][1].w
                   + v2.x * wreg[l][2].x + v2.y * wreg[l][2].y
                   + v2.z * wreg[l][2].z + v2.w * wreg[l][2].w
                   + v3.x * wreg[l][3].x + v3.y * wreg[l][3].y
                   + v3.z * wreg[l][3].z + v3.w * wreg[l][3].w;
        }
#pragma unroll
        for (int l = 0; l < L_; ++l) acc[l] = wave_sum63(acc[l]);
        if (lane == 63) {
            const int lab = (int)(ev & 0xFFu);
            float lg[L_];
#pragma unroll
            for (int l = 0; l < L_; ++l) lg[l] = acc[l] + bl[l];
            float mx = lg[0];
#pragma unroll
            for (int l = 1; l < L_; ++l) mx = fmaxf(mx, lg[l]);
            float se = 0.f;
#pragma unroll
            for (int l = 0; l < L_; ++l) se += __expf(lg[l] - mx);
            float sel = lg[0];
#pragma unroll
            for (int l = 1; l < L_; ++l) sel = (lab == l) ? lg[l] : sel;
            lsum += mx + __logf(se) - sel;
        }
    };

    while (m) {
        const int i0 = __ffsll(m) - 1; m &= m - 1;
        const unsigned e0 = (unsigned)__builtin_amdgcn_readlane((int)e, i0);
        const int slot0 = wid * SLOTS_PER_WAVE + i0;
        const float4* p0 = X4 +
            ((size_t)((slot0 >> 9) << 9) + (e0 >> 8)) * (H_ / 4);
        const float4 a0 = p0[lane];
        const float4 a1 = p0[lane + 64];
        const float4 a2 = p0[lane + 128];
        const float4 a3 = p0[lane + 192];

        if (m) {
            const int i1 = __ffsll(m) - 1; m &= m - 1;
            const unsigned e1 = (unsigned)__builtin_amdgcn_readlane((int)e, i1);
            const int slot1 = wid * SLOTS_PER_WAVE + i1;
            const float4* p1 = X4 +
                ((size_t)((slot1 >> 9) << 9) + (e1 >> 8)) * (H_ / 4);
            const float4 b0 = p1[lane];
            const float4 b1 = p1[lane + 64];
            const float4 b2 = p1[lane + 128];
            const float4 b3 = p1[lane + 192];
            compute(e0, a0, a1, a2, a3);
            compute(e1, b0, b1, b2, b3);
        } else {
            compute(e0, a0, a1, a2, a3);
        }
    }

    __shared__ float ssum[WPB];
    if (lane == 63) ssum[wv] = lsum;
    __syncthreads();
    if (threadIdx.x == 0) {
        float a = 0.f;
#pragma unroll
        for (int w = 0; w < WPB; ++w) a += ssum[w];
        part[blockIdx.x] = a;
    }
}

// ---------------------------------------------------------------------------
// Kernel 3: reduce row-item partials + bias-only partials -> scalar loss
// ---------------------------------------------------------------------------
__global__ void finalize_kernel(const float* __restrict__ part,
                                const float* __restrict__ biassum,
                                const float* __restrict__ actcnt,
                                float* __restrict__ out) {
    const int lane = threadIdx.x;  // 64 threads
    float s = 0.f, c = 0.f;
    for (int i = lane; i < MAIN_BLOCKS; i += 64) s += part[i];
    for (int i = lane; i < B_; i += 64) { s += biassum[i]; c += actcnt[i]; }
#pragma unroll
    for (int off = 32; off > 0; off >>= 1) {
        s += __shfl_xor(s, off, 64);
        c += __shfl_xor(c, off, 64);
    }
    if (lane == 0) out[0] = s / fmaxf(c, 1.0f);
}

extern "C" void kernel_launch(void* const* d_in, const int* in_sizes, int n_in,
                              void* d_out, int out_size, void* d_ws, size_t ws_size,
                              hipStream_t stream) {
    const float* x      = (const float*)d_in[0];  // [B,S,H] f32
    const int*   labels = (const int*)d_in[1];    // [B,S]
    const int*   lmask  = (const int*)d_in[2];    // [B,S]
    const int*   bpe    = (const int*)d_in[3];    // [B,S]
    const float* W      = (const float*)d_in[4];  // [L,H] f32
    const float* bias   = (const float*)d_in[5];  // [L]  f32

    // Workspace layout
    unsigned* work    = (unsigned*)d_ws;                          // B*S u32
    float*    biassum = (float*)((char*)d_ws + (size_t)B_ * S_ * 4);  // [B]
    float*    actcnt  = biassum + B_;                             // [B]
    float*    part    = actcnt + B_;                              // [MAIN_BLOCKS]

    prep_kernel<<<B_, S_, 0, stream>>>(bpe, labels, lmask, bias,
                                       work, biassum, actcnt);
    head_loss_kernel<<<MAIN_BLOCKS, MAIN_THREADS, 0, stream>>>(
        x, W, bias, work, part);
    finalize_kernel<<<1, 64, 0, stream>>>(part, biassum, actcnt, (float*)d_out);
}

// Round 3
// 30.095 us; speedup vs baseline: 1.9608x; 1.3903x over previous
//
#include <hip/hip_runtime.h>
#include <hip/hip_bf16.h>

// Problem-fixed shapes (XLMRForTokenClassification: B=128, S=512, H=1024, L=9)
#define B_ 128
#define S_ 512
#define H_ 1024
#define L_ 9

#define MAIN_BLOCKS  512
#define MAIN_THREADS 256
#define WPB          (MAIN_THREADS / 64)       // 4 waves/block
#define NWAVES       (MAIN_BLOCKS * WPB)       // 2048

// DPP-based wave64 sum: result lands in lane 63.
#define DPP_ADD_(v, ctrl, rm, bm)                                              \
    v += __int_as_float(__builtin_amdgcn_update_dpp(                           \
        0, __float_as_int(v), ctrl, rm, bm, true))

__device__ __forceinline__ float wave_sum63(float v) {
    DPP_ADD_(v, 0x111, 0xf, 0xf);  // row_shr:1
    DPP_ADD_(v, 0x112, 0xf, 0xf);  // row_shr:2
    DPP_ADD_(v, 0x114, 0xf, 0xe);  // row_shr:4
    DPP_ADD_(v, 0x118, 0xf, 0xc);  // row_shr:8
    DPP_ADD_(v, 0x142, 0xa, 0xf);  // row_bcast:15 -> rows 1,3
    DPP_ADD_(v, 0x143, 0xc, 0xf);  // row_bcast:31 -> rows 2,3
    return v;                      // lane 63 holds the 64-lane total
}

// ---------------------------------------------------------------------------
// Kernel 1 (prep): per batch (512 threads):
//  - stable-partition scan -> srcbuf (s-th valid original position)
//  - compact active row-items {(src<<4)|lab} to seg[b*512 + rank] (stable)
//  - rowcnt[b] = #row items
//  - bias-only active positions folded analytically into biassum[b]
//  - actcnt[b] = total active positions (loss denominator)
// ---------------------------------------------------------------------------
__global__ void prep_kernel(const int* __restrict__ bpe,
                            const int* __restrict__ labels,
                            const int* __restrict__ lmask,
                            const float* __restrict__ bias,
                            unsigned* __restrict__ seg,
                            int* __restrict__ rowcnt,
                            float* __restrict__ biassum,
                            float* __restrict__ actcnt) {
    const int b    = blockIdx.x;
    const int s    = threadIdx.x;   // 0..511
    const int lane = s & 63;
    const int wave = s >> 6;        // 0..7

    __shared__ int   wcnt[S_ / 64];
    __shared__ int   wcnt2[S_ / 64];
    __shared__ int   srcbuf[S_];
    __shared__ float rsum[S_ / 64], rcnt[S_ / 64];

    // --- scan 1: valid positions -> srcbuf, n_valid ---
    const int v = (bpe[b * S_ + s] == 1) ? 1 : 0;
    const unsigned long long ball = __ballot(v != 0);
    const int rank = (int)__popcll(ball & ((1ull << lane) - 1ull));
    if (lane == 0) wcnt[wave] = (int)__popcll(ball);
    __syncthreads();

    int prefix = 0, n_valid = 0;
#pragma unroll
    for (int w = 0; w < S_ / 64; ++w) {
        const int c = wcnt[w];
        if (w < wave) prefix += c;
        n_valid += c;
    }
    if (v) srcbuf[prefix + rank] = s;
    __syncthreads();

    // --- scan 2: compact active row-items ---
    const int lab = labels[b * S_ + s];
    const bool act = (lmask[b * S_ + s] == 1) && (lab != 0);
    const bool rowitem = act && (s < n_valid);

    const unsigned long long ball2 = __ballot(rowitem);
    const int rank2 = (int)__popcll(ball2 & ((1ull << lane) - 1ull));
    if (lane == 0) wcnt2[wave] = (int)__popcll(ball2);
    __syncthreads();

    int prefix2 = 0, rowtot = 0;
#pragma unroll
    for (int w = 0; w < S_ / 64; ++w) {
        const int c = wcnt2[w];
        if (w < wave) prefix2 += c;
        rowtot += c;
    }
    if (rowitem)
        seg[b * S_ + prefix2 + rank2] = ((unsigned)srcbuf[s] << 4) | (unsigned)lab;
    if (s == 0) rowcnt[b] = rowtot;

    // --- bias-only items (s >= n_valid: gathered row is zeros) ---
    float bnll = 0.f;
    if (act && s >= n_valid) {
        float mx = bias[0];
#pragma unroll
        for (int l = 1; l < L_; ++l) mx = fmaxf(mx, bias[l]);
        float se = 0.f;
#pragma unroll
        for (int l = 0; l < L_; ++l) se += __expf(bias[l] - mx);
        bnll = mx + __logf(se) - bias[lab];
    }
    float c = act ? 1.f : 0.f;
#pragma unroll
    for (int off = 32; off > 0; off >>= 1) {
        bnll += __shfl_xor(bnll, off, 64);
        c    += __shfl_xor(c, off, 64);
    }
    if (lane == 0) { rsum[wave] = bnll; rcnt[wave] = c; }
    __syncthreads();
    if (s == 0) {
        float a = 0.f, cc = 0.f;
#pragma unroll
        for (int w = 0; w < S_ / 64; ++w) { a += rsum[w]; cc += rcnt[w]; }
        biassum[b] = a;
        actcnt[b]  = cc;
    }
}

// ---------------------------------------------------------------------------
// Kernel 2 (head): 512 blocks x 4 waves. Prologue: per-block scan of rowcnt
// -> bases[] in LDS (wave-0 shfl_up scan). Waves process dense items strided
// by NWAVES (balanced +-1), ping-pong pipelined (next item's meta+row loads
// issued before current item's compute). W in registers; DPP reduction.
// ---------------------------------------------------------------------------
__global__ __launch_bounds__(MAIN_THREADS, 2) void head_loss_kernel(
    const float* __restrict__ x,     // [B,S,H]
    const float* __restrict__ W,     // [L,H]
    const float* __restrict__ bias,  // [L]
    const unsigned* __restrict__ seg,
    const int* __restrict__ rowcnt,
    float* __restrict__ part)        // [MAIN_BLOCKS]
{
    const int lane = threadIdx.x & 63;
    const int wv   = threadIdx.x >> 6;
    const int wid  = blockIdx.x * WPB + wv;

    __shared__ int   bases[B_ + 1];
    __shared__ float ssum[WPB];

    // --- prologue: exclusive scan of rowcnt into bases (wave 0) ---
    if (threadIdx.x < 64) {
        const int c0 = rowcnt[2 * lane];
        const int c1 = rowcnt[2 * lane + 1];
        int ps = c0 + c1;
        int incl = ps;
#pragma unroll
        for (int off = 1; off < 64; off <<= 1) {
            const int t = __shfl_up(incl, off, 64);
            if (lane >= off) incl += t;
        }
        bases[2 * lane]     = incl - ps;
        bases[2 * lane + 1] = incl - c1;
        if (lane == 63) bases[B_] = incl;
    }
    __syncthreads();
    const int n = bases[B_];

    // --- stage W into registers ---
    const float4* W4 = reinterpret_cast<const float4*>(W);
    float4 wreg[L_][4];
#pragma unroll
    for (int l = 0; l < L_; ++l)
#pragma unroll
        for (int k = 0; k < 4; ++k)
            wreg[l][k] = W4[l * (H_ / 4) + lane + 64 * k];

    float bl[L_];
#pragma unroll
    for (int l = 0; l < L_; ++l) bl[l] = bias[l];

    const float4* X4 = reinterpret_cast<const float4*>(x);
    float lsum = 0.f;

    // meta = (b<<16) | (src<<4) | lab
    auto fetch_meta = [&](int g) -> unsigned {
        int lo = 0, hi = B_ - 1;
#pragma unroll
        for (int it = 0; it < 7; ++it) {
            const int mid = (lo + hi + 1) >> 1;
            if (bases[mid] <= g) lo = mid; else hi = mid - 1;
        }
        const unsigned e = seg[lo * S_ + (g - bases[lo])];
        return ((unsigned)lo << 16) | e;
    };
    auto row_ptr = [&](unsigned mt) -> const float4* {
        const int b   = (int)(mt >> 16);
        const int src = (int)((mt >> 4) & 0x1FFu);
        return X4 + ((size_t)b * S_ + src) * (H_ / 4);
    };
    auto compute = [&](unsigned mt, float4 v0, float4 v1, float4 v2, float4 v3) {
        float acc[L_];
#pragma unroll
        for (int l = 0; l < L_; ++l) {
            acc[l] = v0.x * wreg[l][0].x + v0.y * wreg[l][0].y
                   + v0.z * wreg[l][0].z + v0.w * wreg[l][0].w
                   + v1.x * wreg[l][1].x + v1.y * wreg[l][1].y
                   + v1.z * wreg[l][1].z + v1.w * wreg[l][1].w
                   + v2.x * wreg[l][2].x + v2.y * wreg[l][2].y
                   + v2.z * wreg[l][2].z + v2.w * wreg[l][2].w
                   + v3.x * wreg[l][3].x + v3.y * wreg[l][3].y
                   + v3.z * wreg[l][3].z + v3.w * wreg[l][3].w;
        }
#pragma unroll
        for (int l = 0; l < L_; ++l) acc[l] = wave_sum63(acc[l]);
        if (lane == 63) {
            const int lab = (int)(mt & 0xFu);
            float lg[L_];
#pragma unroll
            for (int l = 0; l < L_; ++l) lg[l] = acc[l] + bl[l];
            float mx = lg[0];
#pragma unroll
            for (int l = 1; l < L_; ++l) mx = fmaxf(mx, lg[l]);
            float se = 0.f;
#pragma unroll
            for (int l = 0; l < L_; ++l) se += __expf(lg[l] - mx);
            float sel = lg[0];
#pragma unroll
            for (int l = 1; l < L_; ++l) sel = (lab == l) ? lg[l] : sel;
            lsum += mx + __logf(se) - sel;
        }
    };

    // --- ping-pong pipeline over items g = wid, wid+NWAVES, ... ---
    int gA = wid;
    if (gA < n) {
        unsigned mA = fetch_meta(gA);
        const float4* pA = row_ptr(mA);
        float4 A0 = pA[lane], A1 = pA[lane + 64],
               A2 = pA[lane + 128], A3 = pA[lane + 192];
        int gB = gA + NWAVES;
        for (;;) {
            unsigned mB = 0;
            float4 B0, B1, B2, B3;
            if (gB < n) {
                mB = fetch_meta(gB);
                const float4* pB = row_ptr(mB);
                B0 = pB[lane]; B1 = pB[lane + 64];
                B2 = pB[lane + 128]; B3 = pB[lane + 192];
            }
            compute(mA, A0, A1, A2, A3);
            if (gB >= n) break;
            gA = gB + NWAVES;
            if (gA < n) {
                mA = fetch_meta(gA);
                const float4* pA2 = row_ptr(mA);
                A0 = pA2[lane]; A1 = pA2[lane + 64];
                A2 = pA2[lane + 128]; A3 = pA2[lane + 192];
            }
            compute(mB, B0, B1, B2, B3);
            if (gA >= n) break;
            gB = gA + NWAVES;
        }
    }

    if (lane == 63) ssum[wv] = lsum;
    __syncthreads();
    if (threadIdx.x == 0) {
        float a = 0.f;
#pragma unroll
        for (int w = 0; w < WPB; ++w) a += ssum[w];
        part[blockIdx.x] = a;
    }
}

// ---------------------------------------------------------------------------
// Kernel 3: reduce partials + bias-only sums -> scalar loss
// ---------------------------------------------------------------------------
__global__ void finalize_kernel(const float* __restrict__ part,
                                const float* __restrict__ biassum,
                                const float* __restrict__ actcnt,
                                float* __restrict__ out) {
    const int lane = threadIdx.x;  // 64 threads
    float s = 0.f, c = 0.f;
    for (int i = lane; i < MAIN_BLOCKS; i += 64) s += part[i];
    for (int i = lane; i < B_; i += 64) { s += biassum[i]; c += actcnt[i]; }
#pragma unroll
    for (int off = 32; off > 0; off >>= 1) {
        s += __shfl_xor(s, off, 64);
        c += __shfl_xor(c, off, 64);
    }
    if (lane == 0) out[0] = s / fmaxf(c, 1.0f);
}

extern "C" void kernel_launch(void* const* d_in, const int* in_sizes, int n_in,
                              void* d_out, int out_size, void* d_ws, size_t ws_size,
                              hipStream_t stream) {
    const float* x      = (const float*)d_in[0];  // [B,S,H] f32
    const int*   labels = (const int*)d_in[1];    // [B,S]
    const int*   lmask  = (const int*)d_in[2];    // [B,S]
    const int*   bpe    = (const int*)d_in[3];    // [B,S]
    const float* W      = (const float*)d_in[4];  // [L,H] f32
    const float* bias   = (const float*)d_in[5];  // [L]  f32

    // Workspace layout
    unsigned* seg     = (unsigned*)d_ws;                              // B*S u32
    int*      rowcnt  = (int*)((char*)d_ws + (size_t)B_ * S_ * 4);    // [B]
    float*    biassum = (float*)(rowcnt + B_);                        // [B]
    float*    actcnt  = biassum + B_;                                 // [B]
    float*    part    = actcnt + B_;                                  // [MAIN_BLOCKS]

    prep_kernel<<<B_, S_, 0, stream>>>(bpe, labels, lmask, bias,
                                       seg, rowcnt, biassum, actcnt);
    head_loss_kernel<<<MAIN_BLOCKS, MAIN_THREADS, 0, stream>>>(
        x, W, bias, seg, rowcnt, part);
    finalize_kernel<<<1, 64, 0, stream>>>(part, biassum, actcnt, (float*)d_out);
}